// Round 12
// baseline (261.636 us; speedup 1.0000x reference)
//
#include <hip/hip_runtime.h>
#include <cstdint>

typedef unsigned short ushort_t;
typedef __bf16 bf16x8 __attribute__((ext_vector_type(8)));
typedef float f32x4 __attribute__((ext_vector_type(4)));

#define PI_F 3.14159265358979323846f

__device__ __forceinline__ ushort_t f2bf(float f) {
  uint32_t x = __float_as_uint(f);
  x += 0x7fffu + ((x >> 16) & 1u);
  return (ushort_t)(x >> 16);
}
__device__ __forceinline__ float bf2f(ushort_t u) {
  return __uint_as_float(((uint32_t)u) << 16);
}
__device__ __forceinline__ float softplusf(float x) {
  return (x > 20.f) ? x : log1pf(expf(x));
}
__device__ __forceinline__ void async_ld16(ushort_t* lds, const ushort_t* g) {
  __builtin_amdgcn_global_load_lds(
      (const __attribute__((address_space(1))) uint32_t*)g,
      (__attribute__((address_space(3))) uint32_t*)lds, 16, 0, 0);
}
__device__ __forceinline__ void load16f(const float* p, float* v) {
  const float4* q = reinterpret_cast<const float4*>(p);
  float4 t0 = q[0], t1 = q[1], t2 = q[2], t3 = q[3];
  v[0]=t0.x; v[1]=t0.y; v[2]=t0.z; v[3]=t0.w;
  v[4]=t1.x; v[5]=t1.y; v[6]=t1.z; v[7]=t1.w;
  v[8]=t2.x; v[9]=t2.y; v[10]=t2.z; v[11]=t2.w;
  v[12]=t3.x; v[13]=t3.y; v[14]=t3.z; v[15]=t3.w;
}

// ---------------- elementwise prep ----------------

__global__ __launch_bounds__(256) void cast_bf16(const float* __restrict__ in,
                                                 ushort_t* __restrict__ out, int n) {
  int i = blockIdx.x * 256 + threadIdx.x;
  if (i < n) out[i] = f2bf(in[i]);
}

__global__ __launch_bounds__(256) void zero_f4(float4* __restrict__ p) {
  int i = blockIdx.x * 256 + threadIdx.x;
  p[i] = (float4){0.f, 0.f, 0.f, 0.f};
}

// out[c][r] = in[r][c] * (scale ? scale[c] : 1), f32 -> bf16.  R,C multiples of 32.
__global__ __launch_bounds__(256) void transpose_cast(const float* __restrict__ in,
                                                      ushort_t* __restrict__ out,
                                                      int R, int C,
                                                      const float* __restrict__ scale) {
  __shared__ float t[32][33];
  int bc = blockIdx.x * 32;
  int br = blockIdx.y * 32;
  int tx = threadIdx.x, ty = threadIdx.y;
#pragma unroll
  for (int i = ty; i < 32; i += 8)
    t[i][tx] = in[(size_t)(br + i) * C + bc + tx];
  __syncthreads();
#pragma unroll
  for (int i = ty; i < 32; i += 8) {
    float sv = scale ? scale[bc + i] : 1.f;
    out[(size_t)(bc + i) * R + br + tx] = f2bf(t[tx][i] * sv);
  }
}

// bdt[d][n] = b_proj[d][n] * softplus(dt_proj[d]);  65536 elements
__global__ __launch_bounds__(256) void bdt_kernel(const float* __restrict__ bp,
                                                  const float* __restrict__ dtp,
                                                  float* __restrict__ bdt) {
  int i = blockIdx.x * 256 + threadIdx.x;
  bdt[i] = bp[i] * softplusf(dtp[i >> 4]);
}

// scalars: sc[0]=w0 sc[1]=w1 sc[2]=dtbar sc[8+n]=r_n sc[24+n]=r_n^32
__global__ __launch_bounds__(256) void small_setup(const float* __restrict__ dtp,
                                                   const float* __restrict__ a_log,
                                                   const float* __restrict__ ar,
                                                   const float* __restrict__ ai,
                                                   const float* __restrict__ rot,
                                                   const float* __restrict__ wh,
                                                   float* __restrict__ sc) {
  __shared__ float red[256];
  float s = 0.f;
  for (int i = threadIdx.x; i < 4096; i += 256) s += softplusf(dtp[i]);
  red[threadIdx.x] = s;
  __syncthreads();
  for (int st = 128; st > 0; st >>= 1) {
    if (threadIdx.x < st) red[threadIdx.x] += red[threadIdx.x + st];
    __syncthreads();
  }
  if (threadIdx.x == 0) {
    float dtbar = red[0] / 4096.f;
    float B00 = 0.3f * wh[0], B01 = 0.3f * wh[1], B10 = 0.3f * wh[2], B11 = 0.3f * wh[3];
    float C00 = B00*B00 + B01*B10, C01 = B00*B01 + B01*B11;
    float C10 = B10*B00 + B11*B10, C11 = B10*B01 + B11*B11;
    float D00 = C00*B00 + C01*B10, D01 = C00*B01 + C01*B11;
    float D10 = C10*B00 + C11*B10, D11 = C10*B01 + C11*B11;
    float Ur00 = 1.f - 0.5f*C00, Ur01 = -0.5f*C01, Ur10 = -0.5f*C10, Ur11 = 1.f - 0.5f*C11;
    float Ui00 = B00 - D00/6.f, Ui01 = B01 - D01/6.f, Ui10 = B10 - D10/6.f, Ui11 = B11 - D11/6.f;
    float a0r = ar[0], a0i = ai[0], a1r = ar[1], a1i = ai[1];
#pragma unroll
    for (int d = 0; d < 2; ++d) {
      float c0 = cosf(rot[d*2+0]), s0 = sinf(rot[d*2+0]);
      float c1 = cosf(rot[d*2+1]), s1 = sinf(rot[d*2+1]);
      float t0r = a0r*c0 - a0i*s0, t0i = a0r*s0 + a0i*c0;
      float t1r = a1r*c1 - a1i*s1, t1i = a1r*s1 + a1i*c1;
      a0r = Ur00*t0r - Ui00*t0i + Ur01*t1r - Ui01*t1i;
      a0i = Ur00*t0i + Ui00*t0r + Ur01*t1i + Ui01*t1r;
      a1r = Ur10*t0r - Ui10*t0i + Ur11*t1r - Ui11*t1i;
      a1i = Ur10*t0i + Ui10*t0r + Ur11*t1i + Ui11*t1r;
    }
    float p0 = a0r*a0r + a0i*a0i, p1 = a1r*a1r + a1i*a1i;
    float inv = 1.f / (p0 + p1);
    sc[0] = p0 * inv; sc[1] = p1 * inv; sc[2] = dtbar;
#pragma unroll
    for (int n = 0; n < 16; ++n) {
      float a = -expf(a_log[n]);
      sc[8 + n]  = expf(a * dtbar);
      sc[24 + n] = expf(a * dtbar * 32.f);
    }
  }
}

// ---------------- skinny16: C[M][16] = A[M][K] @ Bm[K][16]  (all f32) ----------------

__global__ __launch_bounds__(256)
void skinny16(const float* __restrict__ A, const float* __restrict__ Bm,
              float* __restrict__ C, int K, int lda) {
  const int m0 = blockIdx.x << 2;
  const int tid = threadIdx.x;
  float acc[4][16];
#pragma unroll
  for (int a = 0; a < 4; ++a)
#pragma unroll
    for (int n = 0; n < 16; ++n) acc[a][n] = 0.f;

  for (int d = tid; d < K; d += 256) {
    float bv[16];
    load16f(Bm + (size_t)d * 16, bv);
    float av[4];
#pragma unroll
    for (int a = 0; a < 4; ++a) av[a] = A[(size_t)(m0 + a) * lda + d];
#pragma unroll
    for (int a = 0; a < 4; ++a)
#pragma unroll
      for (int n = 0; n < 16; ++n) acc[a][n] += av[a] * bv[n];
  }
  __shared__ float sred[4][4][16];
  const int w = tid >> 6, lane = tid & 63;
#pragma unroll
  for (int a = 0; a < 4; ++a)
#pragma unroll
    for (int n = 0; n < 16; ++n) {
      float v = acc[a][n];
#pragma unroll
      for (int off2 = 32; off2 > 0; off2 >>= 1) v += __shfl_down(v, off2);
      if (lane == 0) sred[w][a][n] = v;
    }
  __syncthreads();
  if (tid < 64) {
    int a = tid >> 4, n = tid & 15;
    C[(size_t)(m0 + a) * 16 + n] =
        sred[0][a][n] + sred[1][a][n] + sred[2][a][n] + sred[3][a][n];
  }
}

// ---------------- MFMA GEMM: C[M][N] = A[M][K] @ Bt[N][K]^T (both bf16) ----------------
// FUSE: appends one zero-padded K=16 MFMA tile: acc += h[row][0:16] . cp[col][0:16]
//       (h, cp bf16 [*][16], read direct from global/L2), then bf16 C store.
// OBF=false: f32 unsafeAtomicAdd into Cv (split-K accumulation, Cv pre-zeroed).

template<int BM, int BN, int WR, int WC, bool OBF, bool FUSE>
__global__ __launch_bounds__(256)
void gemm_bf16(const ushort_t* __restrict__ A, const ushort_t* __restrict__ Bt,
               void* __restrict__ Cv, int M, int N, int Kc, int lda, int ldb, int swz,
               const ushort_t* __restrict__ hb, const ushort_t* __restrict__ cp) {
  constexpr int BK = 64;
  constexpr int WMR = BM / WR;
  constexpr int WNC = BN / WC;
  constexpr int MI = WMR / 16;
  constexpr int NI = WNC / 16;
  constexpr int NCA = BM * BK * 2 / 1024;
  constexpr int NCB = BN * BK * 2 / 1024;

  __shared__ ushort_t lA[BM * BK];
  __shared__ ushort_t lB[BN * BK];

  const int tid = threadIdx.x;
  const int w = tid >> 6, lane = tid & 63;
  const int wr = w / WC, wc = w % WC;
  const int r = lane & 15, g = lane >> 4;

  const int nbx = gridDim.x;
  int bid = blockIdx.y * nbx + blockIdx.x;
  if (swz) {
    const int nwg = nbx * gridDim.y;
    bid = (bid & 7) * (nwg >> 3) + (bid >> 3);   // XCD-chunked (nwg%8==0)
  }
  const int m0 = (bid / nbx) * BM, n0 = (bid % nbx) * BN;
  const int kz = blockIdx.z * Kc;

  f32x4 acc[MI][NI];
#pragma unroll
  for (int mi = 0; mi < MI; ++mi)
#pragma unroll
    for (int ni = 0; ni < NI; ++ni)
      acc[mi][ni] = (f32x4){0.f, 0.f, 0.f, 0.f};

  const int ktiles = Kc >> 6;
  for (int kt = 0; kt < ktiles; ++kt) {
    const int k0 = kz + (kt << 6);
    for (int c = w; c < NCA; c += 4) {
      int byteoff = (c << 10) + (lane << 4);
      int row = byteoff >> 7;
      int scol = (byteoff & 127) ^ ((row & 7) << 4);
      async_ld16(&lA[c << 9], &A[(size_t)(m0 + row) * lda + k0 + (scol >> 1)]);
    }
    for (int c = w; c < NCB; c += 4) {
      int byteoff = (c << 10) + (lane << 4);
      int row = byteoff >> 7;
      int scol = (byteoff & 127) ^ ((row & 7) << 4);
      async_ld16(&lB[c << 9], &Bt[(size_t)(n0 + row) * ldb + k0 + (scol >> 1)]);
    }
    __syncthreads();   // drains vmcnt before barrier -> staged data visible
#pragma unroll
    for (int kk = 0; kk < 2; ++kk) {
      bf16x8 av[MI], bv[NI];
#pragma unroll
      for (int mi = 0; mi < MI; ++mi) {
        int row = wr * WMR + mi * 16 + r;
        int off = (((kk << 2) + g) ^ (row & 7)) << 3;   // ushort units (16B chunks)
        av[mi] = *reinterpret_cast<const bf16x8*>(&lA[row * 64 + off]);
      }
#pragma unroll
      for (int ni = 0; ni < NI; ++ni) {
        int row = wc * WNC + ni * 16 + r;
        int off = (((kk << 2) + g) ^ (row & 7)) << 3;
        bv[ni] = *reinterpret_cast<const bf16x8*>(&lB[row * 64 + off]);
      }
#pragma unroll
      for (int mi = 0; mi < MI; ++mi)
#pragma unroll
        for (int ni = 0; ni < NI; ++ni)
          acc[mi][ni] = __builtin_amdgcn_mfma_f32_16x16x32_bf16(av[mi], bv[ni], acc[mi][ni], 0, 0, 0);
    }
    __syncthreads();
  }

  if constexpr (FUSE) {
    // h-term via one zero-padded MFMA per acc tile: k=0..15 live (g<2), k=16..31 zero.
    bf16x8 zv;
#pragma unroll
    for (int t2 = 0; t2 < 8; ++t2) zv[t2] = (__bf16)0.0f;
    bf16x8 ah[MI], bh[NI];
#pragma unroll
    for (int mi = 0; mi < MI; ++mi) {
      ah[mi] = zv;
      if (g < 2) {
        int row = m0 + wr * WMR + mi * 16 + r;
        ah[mi] = *reinterpret_cast<const bf16x8*>(&hb[(size_t)row * 16 + g * 8]);
      }
    }
#pragma unroll
    for (int ni = 0; ni < NI; ++ni) {
      bh[ni] = zv;
      if (g < 2) {
        int col = n0 + wc * WNC + ni * 16 + r;
        bh[ni] = *reinterpret_cast<const bf16x8*>(&cp[(size_t)col * 16 + g * 8]);
      }
    }
#pragma unroll
    for (int mi = 0; mi < MI; ++mi)
#pragma unroll
      for (int ni = 0; ni < NI; ++ni)
        acc[mi][ni] = __builtin_amdgcn_mfma_f32_16x16x32_bf16(ah[mi], bh[ni], acc[mi][ni], 0, 0, 0);
  }

#pragma unroll
  for (int mi = 0; mi < MI; ++mi)
#pragma unroll
    for (int ni = 0; ni < NI; ++ni) {
      int row = m0 + wr * WMR + mi * 16 + g * 4;
      int col = n0 + wc * WNC + ni * 16 + r;
#pragma unroll
      for (int j = 0; j < 4; ++j) {
        size_t idx = (size_t)(row + j) * N + col;
        if (OBF) ((ushort_t*)Cv)[idx] = f2bf(acc[mi][ni][j]);
        else     unsafeAtomicAdd(&((float*)Cv)[idx], acc[mi][ni][j]);
      }
    }
}

// ---------------- per-(b,n) channel: band-mask filter (FFT) + exp-decay scan ----------------
// Output h as bf16 [4096][16] (consumed only by GEMM1's h-MFMA epilogue).

__global__ __launch_bounds__(256)
void freq_ssm(const float* __restrict__ Bhd, const float* __restrict__ sc,
              ushort_t* __restrict__ h) {
  const int blk = blockIdx.x;
  const int b = blk >> 4, n = blk & 15;
  const int tid = threadIdx.x;
  __shared__ float2 X[2048];
  __shared__ float carr[64], pre[64];
  const float w0 = sc[0], w1 = sc[1];
  const float r = sc[8 + n], r32 = sc[24 + n];

  for (int l = tid; l < 2048; l += 256) {
    X[l].x = Bhd[(size_t)(b * 2048 + l) * 16 + n];
    X[l].y = 0.f;
  }
  // forward DIF
  for (int ls = 10; ls >= 0; --ls) {
    int s = 1 << ls;
    __syncthreads();
    for (int q = tid; q < 1024; q += 256) {
      int j = q & (s - 1);
      int base = (q >> ls) << (ls + 1);
      int i0 = base + j, i1 = i0 + s;
      float2 a = X[i0], bb = X[i1];
      X[i0].x = a.x + bb.x; X[i0].y = a.y + bb.y;
      float tx = a.x - bb.x, ty = a.y - bb.y;
      float ang = -PI_F * (float)j / (float)s;
      float sn, cs; sincosf(ang, &sn, &cs);
      X[i1].x = tx * cs - ty * sn;
      X[i1].y = tx * sn + ty * cs;
    }
  }
  __syncthreads();
  // mask (bit-reversed freq order). low band: f<=512 or f>=1536
  for (int i = tid; i < 2048; i += 256) {
    unsigned f = __brev((unsigned)i) >> 21;
    float wv = (f <= 512u || f >= 1536u) ? w0 : w1;
    X[i].x *= wv; X[i].y *= wv;
  }
  // inverse DIT
  for (int ls = 0; ls <= 10; ++ls) {
    int s = 1 << ls;
    __syncthreads();
    for (int q = tid; q < 1024; q += 256) {
      int j = q & (s - 1);
      int base = (q >> ls) << (ls + 1);
      int i0 = base + j, i1 = i0 + s;
      float ang = PI_F * (float)j / (float)s;
      float sn, cs; sincosf(ang, &sn, &cs);
      float2 bb = X[i1];
      float bx = bb.x * cs - bb.y * sn;
      float by = bb.x * sn + bb.y * cs;
      float2 a = X[i0];
      X[i0].x = a.x + bx; X[i0].y = a.y + by;
      X[i1].x = a.x - bx; X[i1].y = a.y - by;
    }
  }
  __syncthreads();
  const float inv = 1.0f / 2048.0f;
  if (tid < 64) {
    float c = 0.f;
    int base = tid * 32;
#pragma unroll
    for (int i = 0; i < 32; ++i) c = r * c + X[base + i].x * inv;
    carr[tid] = c;
  }
  __syncthreads();
  if (tid == 0) {
    float s = 0.f;
    for (int j2 = 0; j2 < 64; ++j2) { pre[j2] = s; s = s * r32 + carr[j2]; }
  }
  __syncthreads();
  if (tid < 64) {
    float s = pre[tid];
    int base = tid * 32;
#pragma unroll
    for (int i = 0; i < 32; ++i) {
      s = r * s + X[base + i].x * inv;
      h[(size_t)(b * 2048 + base + i) * 16 + n] = f2bf(s);
    }
  }
}

// ---------------- launcher ----------------

extern "C" void kernel_launch(void* const* d_in, const int* in_sizes, int n_in,
                              void* d_out, int out_size, void* d_ws, size_t ws_size,
                              hipStream_t stream) {
  (void)in_sizes; (void)n_in; (void)out_size; (void)ws_size;
  const float* x      = (const float*)d_in[0];
  const float* Win    = (const float*)d_in[1];
  const float* Wout   = (const float*)d_in[2];
  const float* a_log  = (const float*)d_in[3];
  const float* b_proj = (const float*)d_in[4];
  const float* c_proj = (const float*)d_in[5];
  const float* dt_proj= (const float*)d_in[6];
  const float* skip   = (const float*)d_in[7];
  const float* ampr   = (const float*)d_in[8];
  const float* ampi   = (const float*)d_in[9];
  const float* rot    = (const float*)d_in[10];
  const float* wh     = (const float*)d_in[11];
  float* out = (float*)d_out;

  char* ws = (char*)d_ws;
  ushort_t* A1  = (ushort_t*)(ws + 0);          //  4 MB  x as bf16  [4096][512]
  ushort_t* Wt1 = (ushort_t*)(ws + 4194304);    //  4 MB  (Win^T * skip) bf16 [4096][512]
  ushort_t* Wt2 = (ushort_t*)(ws + 8388608);    //  4 MB  output_proj^T bf16 [512][4096]
  float*    bdt = (float*)(ws + 12582912);      //  256 KB [4096][16]
  float*    Wb  = (float*)(ws + 12845056);      //  32 KB  [512][16] = Win @ bdt
  float*    Bhd = (float*)(ws + 12910592);      //  256 KB [4096][16] = x @ Wb
  ushort_t* hb  = (ushort_t*)(ws + 13172736);   //  128 KB h bf16 [4096][16]
  ushort_t* cp16= (ushort_t*)(ws + 13303808);   //  128 KB c_proj bf16 [4096][16]
  float*    sc  = (float*)(ws + 13434880);      //  256 B
  ushort_t* y   = (ushort_t*)(ws + 13435136);   // 32 MB  y bf16 [4096][4096]

  zero_f4<<<2048, 256, 0, stream>>>((float4*)out);             // out accumulates atomics
  cast_bf16<<<8192, 256, 0, stream>>>(x, A1, 4096 * 512);
  cast_bf16<<<256, 256, 0, stream>>>(c_proj, cp16, 65536);
  transpose_cast<<<dim3(128, 16), dim3(32, 8), 0, stream>>>(Win, Wt1, 512, 4096, skip);
  transpose_cast<<<dim3(16, 128), dim3(32, 8), 0, stream>>>(Wout, Wt2, 4096, 512, nullptr);
  bdt_kernel<<<256, 256, 0, stream>>>(b_proj, dt_proj, bdt);
  small_setup<<<1, 256, 0, stream>>>(dt_proj, a_log, ampr, ampi, rot, wh, sc);

  // B-path from x directly (f32): Wb = Win@bdt ; Bhd = x@Wb ; h = freq_ssm(Bhd) -> bf16
  skinny16<<<128, 256, 0, stream>>>(Win, bdt, Wb, 4096, 4096);
  skinny16<<<1024, 256, 0, stream>>>(x, Wb, Bhd, 512, 512);
  freq_ssm<<<32, 256, 0, stream>>>(Bhd, sc, hb);

  // GEMM1 fused: y = A1@Wt1'^T + h@c_proj^T  (skip folded into Wt1'; h-term via MFMA)
  gemm_bf16<128, 128, 2, 2, true, true><<<dim3(32, 32), 256, 0, stream>>>(
      A1, Wt1, y, 4096, 4096, 512, 512, 512, 1, hb, cp16);

  // GEMM2 split-K x4, atomic-accumulated into pre-zeroed out (no reduce pass)
  gemm_bf16<64, 128, 1, 4, false, false><<<dim3(4, 64, 4), 256, 0, stream>>>(
      y, Wt2, out, 4096, 512, 1024, 4096, 4096, 1, nullptr, nullptr);
}

// Round 13
// 242.871 us; speedup vs baseline: 1.0773x; 1.0773x over previous
//
#include <hip/hip_runtime.h>
#include <cstdint>

typedef unsigned short ushort_t;
typedef __bf16 bf16x8 __attribute__((ext_vector_type(8)));
typedef float f32x4 __attribute__((ext_vector_type(4)));

#define PI_F 3.14159265358979323846f

__device__ __forceinline__ ushort_t f2bf(float f) {
  uint32_t x = __float_as_uint(f);
  x += 0x7fffu + ((x >> 16) & 1u);
  return (ushort_t)(x >> 16);
}
__device__ __forceinline__ float bf2f(ushort_t u) {
  return __uint_as_float(((uint32_t)u) << 16);
}
__device__ __forceinline__ float softplusf(float x) {
  return (x > 20.f) ? x : log1pf(expf(x));
}
__device__ __forceinline__ void async_ld16(ushort_t* lds, const ushort_t* g) {
  __builtin_amdgcn_global_load_lds(
      (const __attribute__((address_space(1))) uint32_t*)g,
      (__attribute__((address_space(3))) uint32_t*)lds, 16, 0, 0);
}
__device__ __forceinline__ void load16f(const float* p, float* v) {
  const float4* q = reinterpret_cast<const float4*>(p);
  float4 t0 = q[0], t1 = q[1], t2 = q[2], t3 = q[3];
  v[0]=t0.x; v[1]=t0.y; v[2]=t0.z; v[3]=t0.w;
  v[4]=t1.x; v[5]=t1.y; v[6]=t1.z; v[7]=t1.w;
  v[8]=t2.x; v[9]=t2.y; v[10]=t2.z; v[11]=t2.w;
  v[12]=t3.x; v[13]=t3.y; v[14]=t3.z; v[15]=t3.w;
}

// ---------------- elementwise prep ----------------

__global__ __launch_bounds__(256) void cast_bf16(const float* __restrict__ in,
                                                 ushort_t* __restrict__ out, int n) {
  int i = blockIdx.x * 256 + threadIdx.x;
  if (i < n) out[i] = f2bf(in[i]);
}

// out[c][r] = in[r][c] * (scale ? scale[c] : 1), f32 -> bf16.  R,C multiples of 32.
__global__ __launch_bounds__(256) void transpose_cast(const float* __restrict__ in,
                                                      ushort_t* __restrict__ out,
                                                      int R, int C,
                                                      const float* __restrict__ scale) {
  __shared__ float t[32][33];
  int bc = blockIdx.x * 32;
  int br = blockIdx.y * 32;
  int tx = threadIdx.x, ty = threadIdx.y;
#pragma unroll
  for (int i = ty; i < 32; i += 8)
    t[i][tx] = in[(size_t)(br + i) * C + bc + tx];
  __syncthreads();
#pragma unroll
  for (int i = ty; i < 32; i += 8) {
    float sv = scale ? scale[bc + i] : 1.f;
    out[(size_t)(bc + i) * R + br + tx] = f2bf(t[tx][i] * sv);
  }
}

// scalars: sc[0]=w0 sc[1]=w1 sc[2]=dtbar sc[8+n]=r_n sc[24+n]=r_n^32
__global__ __launch_bounds__(256) void small_setup(const float* __restrict__ dtp,
                                                   const float* __restrict__ a_log,
                                                   const float* __restrict__ ar,
                                                   const float* __restrict__ ai,
                                                   const float* __restrict__ rot,
                                                   const float* __restrict__ wh,
                                                   float* __restrict__ sc) {
  __shared__ float red[256];
  float s = 0.f;
  for (int i = threadIdx.x; i < 4096; i += 256) s += softplusf(dtp[i]);
  red[threadIdx.x] = s;
  __syncthreads();
  for (int st = 128; st > 0; st >>= 1) {
    if (threadIdx.x < st) red[threadIdx.x] += red[threadIdx.x + st];
    __syncthreads();
  }
  if (threadIdx.x == 0) {
    float dtbar = red[0] / 4096.f;
    float B00 = 0.3f * wh[0], B01 = 0.3f * wh[1], B10 = 0.3f * wh[2], B11 = 0.3f * wh[3];
    float C00 = B00*B00 + B01*B10, C01 = B00*B01 + B01*B11;
    float C10 = B10*B00 + B11*B10, C11 = B10*B01 + B11*B11;
    float D00 = C00*B00 + C01*B10, D01 = C00*B01 + C01*B11;
    float D10 = C10*B00 + C11*B10, D11 = C10*B01 + C11*B11;
    float Ur00 = 1.f - 0.5f*C00, Ur01 = -0.5f*C01, Ur10 = -0.5f*C10, Ur11 = 1.f - 0.5f*C11;
    float Ui00 = B00 - D00/6.f, Ui01 = B01 - D01/6.f, Ui10 = B10 - D10/6.f, Ui11 = B11 - D11/6.f;
    float a0r = ar[0], a0i = ai[0], a1r = ar[1], a1i = ai[1];
#pragma unroll
    for (int d = 0; d < 2; ++d) {
      float c0 = cosf(rot[d*2+0]), s0 = sinf(rot[d*2+0]);
      float c1 = cosf(rot[d*2+1]), s1 = sinf(rot[d*2+1]);
      float t0r = a0r*c0 - a0i*s0, t0i = a0r*s0 + a0i*c0;
      float t1r = a1r*c1 - a1i*s1, t1i = a1r*s1 + a1i*c1;
      a0r = Ur00*t0r - Ui00*t0i + Ur01*t1r - Ui01*t1i;
      a0i = Ur00*t0i + Ui00*t0r + Ur01*t1i + Ui01*t1r;
      a1r = Ur10*t0r - Ui10*t0i + Ur11*t1r - Ui11*t1i;
      a1i = Ur10*t0i + Ui10*t0r + Ur11*t1i + Ui11*t1r;
    }
    float p0 = a0r*a0r + a0i*a0i, p1 = a1r*a1r + a1i*a1i;
    float inv = 1.f / (p0 + p1);
    sc[0] = p0 * inv; sc[1] = p1 * inv; sc[2] = dtbar;
#pragma unroll
    for (int n = 0; n < 16; ++n) {
      float a = -expf(a_log[n]);
      sc[8 + n]  = expf(a * dtbar);
      sc[24 + n] = expf(a * dtbar * 32.f);
    }
  }
}

// ---------------- skinny16: C[M][16] = A[M][K] @ Bm[K][16]  (all f32) ----------------

__global__ __launch_bounds__(256)
void skinny16(const float* __restrict__ A, const float* __restrict__ Bm,
              float* __restrict__ C, int K, int lda) {
  const int m0 = blockIdx.x << 2;
  const int tid = threadIdx.x;
  float acc[4][16];
#pragma unroll
  for (int a = 0; a < 4; ++a)
#pragma unroll
    for (int n = 0; n < 16; ++n) acc[a][n] = 0.f;

  for (int d = tid; d < K; d += 256) {
    float bv[16];
    load16f(Bm + (size_t)d * 16, bv);
    float av[4];
#pragma unroll
    for (int a = 0; a < 4; ++a) av[a] = A[(size_t)(m0 + a) * lda + d];
#pragma unroll
    for (int a = 0; a < 4; ++a)
#pragma unroll
      for (int n = 0; n < 16; ++n) acc[a][n] += av[a] * bv[n];
  }
  __shared__ float sred[4][4][16];
  const int w = tid >> 6, lane = tid & 63;
#pragma unroll
  for (int a = 0; a < 4; ++a)
#pragma unroll
    for (int n = 0; n < 16; ++n) {
      float v = acc[a][n];
#pragma unroll
      for (int off2 = 32; off2 > 0; off2 >>= 1) v += __shfl_down(v, off2);
      if (lane == 0) sred[w][a][n] = v;
    }
  __syncthreads();
  if (tid < 64) {
    int a = tid >> 4, n = tid & 15;
    C[(size_t)(m0 + a) * 16 + n] =
        sred[0][a][n] + sred[1][a][n] + sred[2][a][n] + sred[3][a][n];
  }
}

// skinny16 with bdt fused on the fly: Wb[M][16] = Win[M][K] @ (b_proj[d]*softplus(dt[d]))

__global__ __launch_bounds__(256)
void skinny16_bdt(const float* __restrict__ A, const float* __restrict__ bp,
                  const float* __restrict__ dtp, float* __restrict__ C,
                  int K, int lda) {
  const int m0 = blockIdx.x << 2;
  const int tid = threadIdx.x;
  float acc[4][16];
#pragma unroll
  for (int a = 0; a < 4; ++a)
#pragma unroll
    for (int n = 0; n < 16; ++n) acc[a][n] = 0.f;

  for (int d = tid; d < K; d += 256) {
    float bv[16];
    load16f(bp + (size_t)d * 16, bv);
    float sp = softplusf(dtp[d]);
    float av[4];
#pragma unroll
    for (int a = 0; a < 4; ++a) av[a] = A[(size_t)(m0 + a) * lda + d];
#pragma unroll
    for (int n = 0; n < 16; ++n) bv[n] *= sp;
#pragma unroll
    for (int a = 0; a < 4; ++a)
#pragma unroll
      for (int n = 0; n < 16; ++n) acc[a][n] += av[a] * bv[n];
  }
  __shared__ float sred[4][4][16];
  const int w = tid >> 6, lane = tid & 63;
#pragma unroll
  for (int a = 0; a < 4; ++a)
#pragma unroll
    for (int n = 0; n < 16; ++n) {
      float v = acc[a][n];
#pragma unroll
      for (int off2 = 32; off2 > 0; off2 >>= 1) v += __shfl_down(v, off2);
      if (lane == 0) sred[w][a][n] = v;
    }
  __syncthreads();
  if (tid < 64) {
    int a = tid >> 4, n = tid & 15;
    C[(size_t)(m0 + a) * 16 + n] =
        sred[0][a][n] + sred[1][a][n] + sred[2][a][n] + sred[3][a][n];
  }
}

// ---------------- MFMA GEMM: C[M][N] = A[M][K] @ Bt[N][K]^T (both bf16) ----------------
// FUSE: appends one zero-padded K=16 MFMA tile: acc += h[row][0:16] . cp[col][0:16]
//       (h, cp bf16 [*][16], read direct from global/L2), then bf16 C store.
// OBF=false: f32 stores to Cv + z*M*N (split-K partials).

template<int BM, int BN, int WR, int WC, bool OBF, bool FUSE>
__global__ __launch_bounds__(256)
void gemm_bf16(const ushort_t* __restrict__ A, const ushort_t* __restrict__ Bt,
               void* __restrict__ Cv, int M, int N, int Kc, int lda, int ldb, int swz,
               const ushort_t* __restrict__ hb, const ushort_t* __restrict__ cp) {
  constexpr int BK = 64;
  constexpr int WMR = BM / WR;
  constexpr int WNC = BN / WC;
  constexpr int MI = WMR / 16;
  constexpr int NI = WNC / 16;
  constexpr int NCA = BM * BK * 2 / 1024;
  constexpr int NCB = BN * BK * 2 / 1024;

  __shared__ ushort_t lA[BM * BK];
  __shared__ ushort_t lB[BN * BK];

  const int tid = threadIdx.x;
  const int w = tid >> 6, lane = tid & 63;
  const int wr = w / WC, wc = w % WC;
  const int r = lane & 15, g = lane >> 4;

  const int nbx = gridDim.x;
  int bid = blockIdx.y * nbx + blockIdx.x;
  if (swz) {
    const int nwg = nbx * gridDim.y;
    bid = (bid & 7) * (nwg >> 3) + (bid >> 3);   // XCD-chunked (nwg%8==0)
  }
  const int m0 = (bid / nbx) * BM, n0 = (bid % nbx) * BN;
  const int kz = blockIdx.z * Kc;

  f32x4 acc[MI][NI];
#pragma unroll
  for (int mi = 0; mi < MI; ++mi)
#pragma unroll
    for (int ni = 0; ni < NI; ++ni)
      acc[mi][ni] = (f32x4){0.f, 0.f, 0.f, 0.f};

  const int ktiles = Kc >> 6;
  for (int kt = 0; kt < ktiles; ++kt) {
    const int k0 = kz + (kt << 6);
    for (int c = w; c < NCA; c += 4) {
      int byteoff = (c << 10) + (lane << 4);
      int row = byteoff >> 7;
      int scol = (byteoff & 127) ^ ((row & 7) << 4);
      async_ld16(&lA[c << 9], &A[(size_t)(m0 + row) * lda + k0 + (scol >> 1)]);
    }
    for (int c = w; c < NCB; c += 4) {
      int byteoff = (c << 10) + (lane << 4);
      int row = byteoff >> 7;
      int scol = (byteoff & 127) ^ ((row & 7) << 4);
      async_ld16(&lB[c << 9], &Bt[(size_t)(n0 + row) * ldb + k0 + (scol >> 1)]);
    }
    __syncthreads();   // drains vmcnt before barrier -> staged data visible
#pragma unroll
    for (int kk = 0; kk < 2; ++kk) {
      bf16x8 av[MI], bv[NI];
#pragma unroll
      for (int mi = 0; mi < MI; ++mi) {
        int row = wr * WMR + mi * 16 + r;
        int off = (((kk << 2) + g) ^ (row & 7)) << 3;   // ushort units (16B chunks)
        av[mi] = *reinterpret_cast<const bf16x8*>(&lA[row * 64 + off]);
      }
#pragma unroll
      for (int ni = 0; ni < NI; ++ni) {
        int row = wc * WNC + ni * 16 + r;
        int off = (((kk << 2) + g) ^ (row & 7)) << 3;
        bv[ni] = *reinterpret_cast<const bf16x8*>(&lB[row * 64 + off]);
      }
#pragma unroll
      for (int mi = 0; mi < MI; ++mi)
#pragma unroll
        for (int ni = 0; ni < NI; ++ni)
          acc[mi][ni] = __builtin_amdgcn_mfma_f32_16x16x32_bf16(av[mi], bv[ni], acc[mi][ni], 0, 0, 0);
    }
    __syncthreads();
  }

  if constexpr (FUSE) {
    // h-term via one zero-padded MFMA per acc tile: k=0..15 live (g<2), k=16..31 zero.
    bf16x8 zv;
#pragma unroll
    for (int t2 = 0; t2 < 8; ++t2) zv[t2] = (__bf16)0.0f;
    bf16x8 ah[MI], bh[NI];
#pragma unroll
    for (int mi = 0; mi < MI; ++mi) {
      ah[mi] = zv;
      if (g < 2) {
        int row = m0 + wr * WMR + mi * 16 + r;
        ah[mi] = *reinterpret_cast<const bf16x8*>(&hb[(size_t)row * 16 + g * 8]);
      }
    }
#pragma unroll
    for (int ni = 0; ni < NI; ++ni) {
      bh[ni] = zv;
      if (g < 2) {
        int col = n0 + wc * WNC + ni * 16 + r;
        bh[ni] = *reinterpret_cast<const bf16x8*>(&cp[(size_t)col * 16 + g * 8]);
      }
    }
#pragma unroll
    for (int mi = 0; mi < MI; ++mi)
#pragma unroll
      for (int ni = 0; ni < NI; ++ni)
        acc[mi][ni] = __builtin_amdgcn_mfma_f32_16x16x32_bf16(ah[mi], bh[ni], acc[mi][ni], 0, 0, 0);
  }

  const size_t zoff = (size_t)blockIdx.z * (size_t)M * (size_t)N;
#pragma unroll
  for (int mi = 0; mi < MI; ++mi)
#pragma unroll
    for (int ni = 0; ni < NI; ++ni) {
      int row = m0 + wr * WMR + mi * 16 + g * 4;
      int col = n0 + wc * WNC + ni * 16 + r;
#pragma unroll
      for (int j = 0; j < 4; ++j) {
        size_t idx = zoff + (size_t)(row + j) * N + col;
        if (OBF) ((ushort_t*)Cv)[idx] = f2bf(acc[mi][ni][j]);
        else     ((float*)Cv)[idx]   = acc[mi][ni][j];
      }
    }
}

// ---------------- split-K reduce: out = sum of 4 partials (f32) ----------------

__global__ __launch_bounds__(256)
void reduceK(const float4* __restrict__ p, float4* __restrict__ out) {
  int i = blockIdx.x * 256 + threadIdx.x;   // < 524288
  float4 a = p[i];
  float4 b = p[i + 524288];
  float4 c = p[i + 1048576];
  float4 d = p[i + 1572864];
  float4 o;
  o.x = a.x + b.x + c.x + d.x;
  o.y = a.y + b.y + c.y + d.y;
  o.z = a.z + b.z + c.z + d.z;
  o.w = a.w + b.w + c.w + d.w;
  out[i] = o;
}

// ---------------- per-(b,n) channel: band-mask filter (FFT) + exp-decay scan ----------------
// 512 threads; twiddles from one LDS table T[k]=(cos,sin)(pi*k/1024), idx = j<<(10-ls).
// Output h as bf16 [4096][16].

__global__ __launch_bounds__(512)
void freq_ssm(const float* __restrict__ Bhd, const float* __restrict__ sc,
              ushort_t* __restrict__ h) {
  const int blk = blockIdx.x;
  const int b = blk >> 4, n = blk & 15;
  const int tid = threadIdx.x;
  __shared__ float2 X[2048];
  __shared__ float2 TW[1024];
  __shared__ float carr[64], pre[64];
  const float w0 = sc[0], w1 = sc[1];
  const float r = sc[8 + n], r32 = sc[24 + n];

  for (int l = tid; l < 2048; l += 512) {
    X[l].x = Bhd[(size_t)(b * 2048 + l) * 16 + n];
    X[l].y = 0.f;
  }
  for (int k = tid; k < 1024; k += 512) {
    float sn, cs;
    sincosf(PI_F * (float)k * (1.0f / 1024.0f), &sn, &cs);
    TW[k].x = cs; TW[k].y = sn;
  }
  // forward DIF (twiddle angle -pi*j/s: cs=T.x, sn=-T.y)
  for (int ls = 10; ls >= 0; --ls) {
    int s = 1 << ls;
    __syncthreads();
    for (int q = tid; q < 1024; q += 512) {
      int j = q & (s - 1);
      int base = (q >> ls) << (ls + 1);
      int i0 = base + j, i1 = i0 + s;
      float2 a = X[i0], bb = X[i1];
      X[i0].x = a.x + bb.x; X[i0].y = a.y + bb.y;
      float tx = a.x - bb.x, ty = a.y - bb.y;
      float2 t = TW[j << (10 - ls)];
      X[i1].x = tx * t.x + ty * t.y;
      X[i1].y = ty * t.x - tx * t.y;
    }
  }
  __syncthreads();
  // mask (bit-reversed freq order). low band: f<=512 or f>=1536
  for (int i = tid; i < 2048; i += 512) {
    unsigned f = __brev((unsigned)i) >> 21;
    float wv = (f <= 512u || f >= 1536u) ? w0 : w1;
    X[i].x *= wv; X[i].y *= wv;
  }
  // inverse DIT (twiddle angle +pi*j/s: cs=T.x, sn=+T.y)
  for (int ls = 0; ls <= 10; ++ls) {
    int s = 1 << ls;
    __syncthreads();
    for (int q = tid; q < 1024; q += 512) {
      int j = q & (s - 1);
      int base = (q >> ls) << (ls + 1);
      int i0 = base + j, i1 = i0 + s;
      float2 t = TW[j << (10 - ls)];
      float2 bb = X[i1];
      float bx = bb.x * t.x - bb.y * t.y;
      float by = bb.x * t.y + bb.y * t.x;
      float2 a = X[i0];
      X[i0].x = a.x + bx; X[i0].y = a.y + by;
      X[i1].x = a.x - bx; X[i1].y = a.y - by;
    }
  }
  __syncthreads();
  const float inv = 1.0f / 2048.0f;
  if (tid < 64) {
    float c = 0.f;
    int base = tid * 32;
#pragma unroll
    for (int i = 0; i < 32; ++i) c = r * c + X[base + i].x * inv;
    carr[tid] = c;
  }
  __syncthreads();
  if (tid == 0) {
    float s = 0.f;
    for (int j2 = 0; j2 < 64; ++j2) { pre[j2] = s; s = s * r32 + carr[j2]; }
  }
  __syncthreads();
  if (tid < 64) {
    float s = pre[tid];
    int base = tid * 32;
#pragma unroll
    for (int i = 0; i < 32; ++i) {
      s = r * s + X[base + i].x * inv;
      h[(size_t)(b * 2048 + base + i) * 16 + n] = f2bf(s);
    }
  }
}

// ---------------- launcher ----------------

extern "C" void kernel_launch(void* const* d_in, const int* in_sizes, int n_in,
                              void* d_out, int out_size, void* d_ws, size_t ws_size,
                              hipStream_t stream) {
  (void)in_sizes; (void)n_in; (void)out_size; (void)ws_size;
  const float* x      = (const float*)d_in[0];
  const float* Win    = (const float*)d_in[1];
  const float* Wout   = (const float*)d_in[2];
  const float* a_log  = (const float*)d_in[3];
  const float* b_proj = (const float*)d_in[4];
  const float* c_proj = (const float*)d_in[5];
  const float* dt_proj= (const float*)d_in[6];
  const float* skip   = (const float*)d_in[7];
  const float* ampr   = (const float*)d_in[8];
  const float* ampi   = (const float*)d_in[9];
  const float* rot    = (const float*)d_in[10];
  const float* wh     = (const float*)d_in[11];
  float* out = (float*)d_out;

  char* ws = (char*)d_ws;
  ushort_t* A1  = (ushort_t*)(ws + 0);          //  4 MB  x as bf16  [4096][512]
  ushort_t* Wt1 = (ushort_t*)(ws + 4194304);    //  4 MB  (Win^T * skip) bf16 [4096][512]
  ushort_t* Wt2 = (ushort_t*)(ws + 8388608);    //  4 MB  output_proj^T bf16 [512][4096]
  float*    Wb  = (float*)(ws + 12582912);      //  32 KB  [512][16] = Win @ bdt
  float*    Bhd = (float*)(ws + 12615680);      //  256 KB [4096][16] = x @ Wb
  ushort_t* hb  = (ushort_t*)(ws + 12877824);   //  128 KB h bf16 [4096][16]
  ushort_t* cp16= (ushort_t*)(ws + 13008896);   //  128 KB c_proj bf16 [4096][16]
  float*    sc  = (float*)(ws + 13139968);      //  256 B
  ushort_t* y   = (ushort_t*)(ws + 13140224);   // 32 MB  y bf16 [4096][4096]
  float*    part= (float*)(ws + 46694656);      // 32 MB  split-K partials

  cast_bf16<<<8192, 256, 0, stream>>>(x, A1, 4096 * 512);
  cast_bf16<<<256, 256, 0, stream>>>(c_proj, cp16, 65536);
  transpose_cast<<<dim3(128, 16), dim3(32, 8), 0, stream>>>(Win, Wt1, 512, 4096, skip);
  transpose_cast<<<dim3(16, 128), dim3(32, 8), 0, stream>>>(Wout, Wt2, 4096, 512, nullptr);
  small_setup<<<1, 256, 0, stream>>>(dt_proj, a_log, ampr, ampi, rot, wh, sc);

  // B-path from x directly (f32): Wb = Win@(b_proj*softplus(dt)) ; Bhd = x@Wb ; h = freq_ssm(Bhd)
  skinny16_bdt<<<128, 256, 0, stream>>>(Win, b_proj, dt_proj, Wb, 4096, 4096);
  skinny16<<<1024, 256, 0, stream>>>(x, Wb, Bhd, 512, 512);
  freq_ssm<<<32, 512, 0, stream>>>(Bhd, sc, hb);

  // GEMM1 fused: y = A1@Wt1'^T + h@c_proj^T  (skip folded into Wt1'; h-term via MFMA)
  gemm_bf16<128, 128, 2, 2, true, true><<<dim3(32, 32), 256, 0, stream>>>(
      A1, Wt1, y, 4096, 4096, 512, 512, 512, 1, hb, cp16);

  // GEMM2 split-K x4 -> f32 partials, then reduce
  gemm_bf16<64, 128, 1, 4, false, false><<<dim3(4, 64, 4), 256, 0, stream>>>(
      y, Wt2, part, 4096, 512, 1024, 4096, 4096, 1, nullptr, nullptr);
  reduceK<<<2048, 256, 0, stream>>>((const float4*)part, (float4*)out);
}